// Round 2
// baseline (134.667 us; speedup 1.0000x reference)
//
#include <hip/hip_runtime.h>
#include <hip/hip_bf16.h>
#include <math.h>

// CrossGeometricStructureEmbedding, round 9.
// R8 post-mortem: 66.3us, occupancy fix worked (+13%) but LDS read pipe is
// now the binding resource: SQ_LDS_BANK_CONFLICT = exactly 4 cy per
// ds_read_b128 (2^23 total) == m134's intrinsic 12cy/op b128 ceiling
// (85 B/cy). Read traffic 8.4MB/CU = 98.7K cy vs 159K kernel = 62% busy.
// Traffic is structural (8 waves x full E tile; more cols/wave busts the
// 128-reg 4-waves/SIMD budget). R9 attacks the remaining ~30% stall gap:
// (1) explicit depth-2 A-frag software pipeline (pf[2][2], +16 VGPR);
// (2) loadW(1) hoisted to tail of phase 7 (overlaps epilogue+barrier,
//     removes the phase-8 L2 stall);
// (3) fills shifted to ks=2,6,10,14 after the MFMAs (clean read burst at
//     phase start); s_setprio(1) around MFMA pair (anti-phased blocks give
//     scheduler role diversity);
// (4) treed epilogue max (depth ~3 with max3 fusion).
// VGPR budget: bw 64 + acc 32 (AGPR) + pf 16 + temps ~ 112 <= 128.

typedef __attribute__((ext_vector_type(8))) short short8;
typedef __attribute__((ext_vector_type(16))) float f32x16;
typedef __attribute__((ext_vector_type(4))) unsigned int uint4v;

#define HH 256
#define P_PTS 8
#define NPTS 4096

__device__ __forceinline__ unsigned short f2bf(float f) {
    union { float f; unsigned int u; } v; v.f = f;
    unsigned int r = v.u + 0x7fffu + ((v.u >> 16) & 1u);  // RNE
    return (unsigned short)(r >> 16);
}

__device__ __forceinline__ unsigned int pack_sc(float s, float c) {
    union { __hip_bfloat162 h; unsigned int u; } v;
    v.h = __float22bfloat162_rn(make_float2(s, c));  // low = sin, high = cos
    return v.u;
}

__global__ __launch_bounds__(256)
void prep_w_kernel(const float* __restrict__ Wa, const float* __restrict__ Wd,
                   unsigned short* __restrict__ wbf) {
    int i = blockIdx.x * 256 + threadIdx.x;
    if (i < HH * HH) {
        wbf[i] = f2bf(Wd[i]);             // [0, 65536): Wd bf16
        wbf[HH * HH + i] = f2bf(Wa[i]);   // [65536, 131072): Wa bf16
    }
}

// E swizzle: chunk ch (16B) of row r lives at byte offset
//   r*512 + ((ch ^ (r&7)) << 4)  ==  (r*512 ^ ((r&7)<<4)) ^ (ch<<4)
// XOR-decomposed so each access is base ^ compile-time-const.

__global__ __launch_bounds__(512, 4)
void cgse_main(const float* __restrict__ points,
               const float* __restrict__ anchors,
               const unsigned short* __restrict__ wbf,
               const float* __restrict__ ba,
               const float* __restrict__ bd,
               float* __restrict__ out) {
    __shared__ __align__(16) unsigned short E[2][64 * HH];  // 64 KB dbuf
    __shared__ float dms[P_PTS][HH];                        // 8 KB d-pass maxes
    __shared__ float xsd[P_PTS][64], xsa[P_PTS][64];        // 4 KB
    __shared__ float anch[192];

    const int tid = threadIdx.x;
    const int wave = tid >> 6, lane = tid & 63;
    const int l5 = lane & 31, half = lane >> 5;
    const int base = blockIdx.x * P_PTS;
    const int col = wave * 32 + l5;  // this wave's output column (one of 256)

    // ---- anchors, then geometry: 512 tasks / 512 threads (pt = wave, k = lane)
    if (tid < 192) anch[tid] = anchors[tid];
    __syncthreads();
    {
        const int k2 = (lane + 1) & 63;
        const int pn = base + wave;
        const float px = points[pn * 3 + 0], py = points[pn * 3 + 1], pz = points[pn * 3 + 2];
        const float r1x = px - anch[lane * 3 + 0];
        const float r1y = py - anch[lane * 3 + 1];
        const float r1z = pz - anch[lane * 3 + 2];
        const float r2x = px - anch[k2 * 3 + 0];
        const float r2y = py - anch[k2 * 3 + 1];
        const float r2z = pz - anch[k2 * 3 + 2];
        xsd[wave][lane] = sqrtf(r1x * r1x + r1y * r1y + r1z * r1z) * 5.0f;  // /SIGMA_D
        const float cx = r1y * r2z - r1z * r2y;
        const float cy = r1z * r2x - r1x * r2z;
        const float cz = r1x * r2y - r1y * r2x;
        const float sv = sqrtf(cx * cx + cy * cy + cz * cz);
        const float cv = r1x * r2x + r1y * r2y + r1z * r2z;
        xsa[wave][lane] = atan2f(sv, cv) * 3.8197186342054885f;  // *180/(15*pi)
    }

    const float bias = ba[col] + bd[col];

    // ---- fill constants: omega_i = x * rho^i / 2pi, rho = 1e4^(-1/128) = 10^(-1/32).
    // wave fills chunks 4w..4w+3; chunk factor 10^(-ch/8) = 10^(-w/2) * 10^(-c/8).
    const float cw = 0.15915494309189535f * __expf(-(float)wave * 1.1512925464970227f);

    // XOR-decomposed address bases (bytes)
    const int wbase = (lane << 9) ^ ((lane & 7) << 4) ^ (wave << 6);  // fill: ch = 4w+c
    int rbase[2];
    rbase[0] = (l5 << 9) ^ ((l5 & 7) << 4) ^ (half << 4);             // read: ch = 2ks+half
    rbase[1] = rbase[0] + (32 << 9);

    // fill one 16B chunk: row = lane, chunk = 4*wave + c (c compile-time).
    // t in revolutions, < 10 rev << 256-rev valid domain of v_sin/v_cos.
    auto fill_chunk = [&](char* eb, int c, float xr) {
        const float DC[4] = {1.0f, 0.7498942093324559f, 0.5623413251903491f,
                             0.4216965034285822f};
        const float t0 = xr * DC[c];
        const float t[4] = {t0, t0 * 0.9305720409297085f,
                            t0 * 0.8659643233600653f, t0 * 0.8058421877614819f};
        uint4v w;
        #pragma unroll
        for (int j = 0; j < 4; ++j)
            w[j] = pack_sc(__builtin_amdgcn_sinf(t[j]), __builtin_amdgcn_cosf(t[j]));
        *(uint4v*)(eb + (wbase ^ (c << 4))) = w;
    };

    // ---- W strip (one type) in registers: 16 ks x short8 = 64 VGPRs
    short8 bw[16];
    auto loadW = [&](int t) {
        const unsigned short* wr = wbf + t * (HH * HH) + col * HH + half * 8;
        #pragma unroll
        for (int ks = 0; ks < 16; ++ks)
            bw[ks] = *(const short8*)(wr + ks * 16);
    };

    loadW(0);
    __syncthreads();  // xsd/xsa ready
    // prologue: fill buf0 for phase 0 (point 0, d-type)
    {
        const float xr = xsd[0][lane] * cw;
        #pragma unroll
        for (int c = 0; c < 4; ++c) fill_chunk((char*)E[0], c, xr);
    }

    // 16 phases: 0..7 = d-pass (pt 0..7), 8..15 = a-pass (pt 0..7)
    #pragma unroll 1
    for (int ph = 0; ph < 16; ++ph) {
        __syncthreads();  // E[ph&1] filled; E[ph&1 ^1] free
        const int b = ph & 1;

        const bool dofill = (ph + 1) < 16;
        float xr = 0.f;
        if (dofill) {
            const int pn = (ph + 1) & 7;
            xr = ((ph + 1) < 8 ? xsd[pn][lane] : xsa[pn][lane]) * cw;
        }

        const char* ebC = (const char*)E[b];
        char* ebN = (char*)E[b ^ 1];

        f32x16 acc[2];
        #pragma unroll
        for (int mt = 0; mt < 2; ++mt)
            #pragma unroll
            for (int r = 0; r < 16; ++r) acc[mt][r] = 0.f;

        // depth-2 A-frag software pipeline: ks and ks+1 in flight
        short8 pf[2][2];
        #pragma unroll
        for (int mt = 0; mt < 2; ++mt) {
            pf[0][mt] = *(const short8*)(ebC + (rbase[mt] ^ (0 << 5)));
            pf[1][mt] = *(const short8*)(ebC + (rbase[mt] ^ (1 << 5)));
        }

        #pragma unroll
        for (int ks = 0; ks < 16; ++ks) {
            const int cur = ks & 1;
            __builtin_amdgcn_s_setprio(1);
            acc[0] = __builtin_amdgcn_mfma_f32_32x32x16_bf16(
                pf[cur][0], bw[ks], acc[0], 0, 0, 0);
            acc[1] = __builtin_amdgcn_mfma_f32_32x32x16_bf16(
                pf[cur][1], bw[ks], acc[1], 0, 0, 0);
            __builtin_amdgcn_s_setprio(0);
            if (ks + 2 < 16) {
                pf[cur][0] = *(const short8*)(ebC + (rbase[0] ^ ((ks + 2) << 5)));
                pf[cur][1] = *(const short8*)(ebC + (rbase[1] ^ ((ks + 2) << 5)));
            }
            if (dofill && (ks & 3) == 2) fill_chunk(ebN, ks >> 2, xr);
        }

        // Wa prefetch: bw dead after ks=15 of phase 7; loads overlap
        // epilogue + barrier instead of stalling phase 8.
        if (ph == 7) loadW(1);

        // epilogue: max over 64 anchors (treed; max3-fusable). C layout:
        // col=lane&31, rows split by lane-half; shfl_down(32) merges halves.
        const int q = ph & 7;
        float t8[8];
        #pragma unroll
        for (int r = 0; r < 8; ++r)
            t8[r] = fmaxf(fmaxf(acc[0][2 * r], acc[0][2 * r + 1]),
                          fmaxf(acc[1][2 * r], acc[1][2 * r + 1]));
        const float ta = fmaxf(fmaxf(t8[0], t8[1]), fmaxf(t8[2], t8[3]));
        const float tb = fmaxf(fmaxf(t8[4], t8[5]), fmaxf(t8[6], t8[7]));
        float m = fmaxf(ta, tb);
        m = fmaxf(m, __shfl_down(m, 32));
        if (lane < 32) {
            if (ph < 8) dms[q][col] = m;
            else out[(base + q) * HH + col] = m + dms[q][col] + bias;
        }
    }
}

extern "C" void kernel_launch(void* const* d_in, const int* in_sizes, int n_in,
                              void* d_out, int out_size, void* d_ws, size_t ws_size,
                              hipStream_t stream) {
    const float* points  = (const float*)d_in[0];
    const float* anchors = (const float*)d_in[1];
    // d_in[2] = cor_score: unused by the reference
    const float* Wa = (const float*)d_in[3];
    const float* ba = (const float*)d_in[4];
    const float* Wd = (const float*)d_in[5];
    const float* bd = (const float*)d_in[6];

    unsigned short* wbf = (unsigned short*)d_ws;  // 256 KB: Wd|Wa bf16

    hipLaunchKernelGGL(prep_w_kernel, dim3(256), dim3(256), 0, stream, Wa, Wd, wbf);
    hipLaunchKernelGGL(cgse_main, dim3(NPTS / P_PTS), dim3(512), 0, stream,
                       points, anchors, wbf, ba, bd, (float*)d_out);
}

// Round 3
// 133.407 us; speedup vs baseline: 1.0094x; 1.0094x over previous
//
#include <hip/hip_runtime.h>
#include <hip/hip_bf16.h>
#include <math.h>

// CrossGeometricStructureEmbedding, round 10.
// R9 post-mortem: loadW-hoist + manual pipeline spilled (WRITE_SIZE 4->13MB,
// FETCH +3.8MB = scratch traffic); discarded. R8 analysis stands: LDS read
// pipe is the top resource (8MB/CU = 41us pipe time of 66us kernel) and the
// traffic is structural: every wave reads full E (A-operand) from LDS each
// phase while W sits in regs. R10 inverts the dataflow: W staged in LDS
// (128KB, shared by all 8 waves), E generated directly into 128 VGPRs by
// each wave for its own point (sincos cost 256 trans/pt-pass, trans pipe
// <20%). Traffic: 8 waves x 2pts x 2passes x 128KB = 4MB/CU (half of R8),
// each b128 read feeds 2 MFMAs, reads are dependency-free (A in regs), and
// per-phase barriers vanish (3 total). Grid 256 = 1 block/CU, 16 pts/block,
// 2 pts/wave. Regs: af 128 + acc 32 + dm 16 + bias 8 + temps ~210 under
// (512,2)=256 cap. LDS 140KB static. Swizzle/fragment layouts carried
// verbatim from R8's verified mappings.

typedef __attribute__((ext_vector_type(8))) short short8;
typedef __attribute__((ext_vector_type(16))) float f32x16;
typedef __attribute__((ext_vector_type(4))) unsigned int uint4v;

#define HH 256
#define BPTS 16
#define NPTS 4096

__device__ __forceinline__ unsigned short f2bf(float f) {
    union { float f; unsigned int u; } v; v.f = f;
    unsigned int r = v.u + 0x7fffu + ((v.u >> 16) & 1u);  // RNE
    return (unsigned short)(r >> 16);
}

__device__ __forceinline__ unsigned int pack_sc(float s, float c) {
    union { __hip_bfloat162 h; unsigned int u; } v;
    v.h = __float22bfloat162_rn(make_float2(s, c));  // low = sin, high = cos
    return v.u;
}

__global__ __launch_bounds__(256)
void prep_w_kernel(const float* __restrict__ Wa, const float* __restrict__ Wd,
                   unsigned short* __restrict__ wbf) {
    int i = blockIdx.x * 256 + threadIdx.x;
    if (i < HH * HH) {
        wbf[i] = f2bf(Wd[i]);             // [0, 65536): Wd bf16
        wbf[HH * HH + i] = f2bf(Wa[i]);   // [65536, 131072): Wa bf16
    }
}

// W LDS swizzle (same family as R8's E swizzle): 16B chunk ch of row o lives
// at byte offset o*512 + ((ch ^ (o&7)) << 4). XOR-decomposes into
// (o<<9) ^ ((o&7)<<4) ^ (half<<4) ^ (ks<<5) for the read side.

__global__ __launch_bounds__(512, 2)
void cgse_main(const float* __restrict__ points,
               const float* __restrict__ anchors,
               const unsigned short* __restrict__ wbf,
               const float* __restrict__ ba,
               const float* __restrict__ bd,
               float* __restrict__ out) {
    __shared__ __align__(16) unsigned short Wlds[HH * HH / 2 * 2];  // 128 KB
    __shared__ float xs[2][BPTS][64];                               // 8 KB
    __shared__ float anch[192];

    const int tid = threadIdx.x;
    const int wave = tid >> 6, lane = tid & 63;
    const int l5 = lane & 31, half = lane >> 5;
    const int base = blockIdx.x * BPTS;

    // ---- geometry: 16 pts x 64 anchors = 1024 tasks / 512 threads
    if (tid < 192) anch[tid] = anchors[tid];
    __syncthreads();
    #pragma unroll
    for (int rep = 0; rep < 2; ++rep) {
        const int task = rep * 512 + tid;
        const int pt = task >> 6, k = task & 63, k2 = (k + 1) & 63;
        const int pn = base + pt;
        const float px = points[pn * 3 + 0], py = points[pn * 3 + 1], pz = points[pn * 3 + 2];
        const float r1x = px - anch[k * 3 + 0];
        const float r1y = py - anch[k * 3 + 1];
        const float r1z = pz - anch[k * 3 + 2];
        const float r2x = px - anch[k2 * 3 + 0];
        const float r2y = py - anch[k2 * 3 + 1];
        const float r2z = pz - anch[k2 * 3 + 2];
        xs[0][pt][k] = sqrtf(r1x * r1x + r1y * r1y + r1z * r1z) * 5.0f;  // /SIGMA_D
        const float cx = r1y * r2z - r1z * r2y;
        const float cy = r1z * r2x - r1x * r2z;
        const float cz = r1x * r2y - r1y * r2x;
        const float sv = sqrtf(cx * cx + cy * cy + cz * cz);
        const float cv = r1x * r2x + r1y * r2y + r1z * r2z;
        xs[1][pt][k] = atan2f(sv, cv) * 3.8197186342054885f;  // *180/(15*pi)
    }

    // per-lane bias for each column tile: col = nt*32 + l5
    float bias[8];
    #pragma unroll
    for (int nt = 0; nt < 8; ++nt)
        bias[nt] = ba[nt * 32 + l5] + bd[nt * 32 + l5];

    float dm[2][8];  // d-pass maxes for this wave's 2 points

    #pragma unroll 1
    for (int pass = 0; pass < 2; ++pass) {
        __syncthreads();  // pass0: xs ready; pass1: all Wd reads retired
        // ---- stage W(pass) into LDS, swizzled. 8192 16B chunks / 512 thr.
        {
            const uint4v* __restrict__ src = (const uint4v*)(wbf + pass * HH * HH);
            #pragma unroll
            for (int it = 0; it < 16; ++it) {
                const int c = it * 512 + tid;
                const uint4v v = src[c];
                const int o = c >> 5, ch = c & 31;
                *(uint4v*)((char*)Wlds + o * 512 + (((ch ^ (o & 7)) & 31) << 4)) = v;
            }
        }
        __syncthreads();

        #pragma unroll
        for (int p = 0; p < 2; ++p) {
            const int pt = wave + p * 8;

            // ---- A-gen: E[row = mt*32+l5][h = 16ks+8half+0..7] into regs.
            // omega_i = x * (1/2pi) * 10^(-i/32); frag covers i = 8ks+4half+{0..3}.
            short8 af[2][16];
            #pragma unroll
            for (int mt = 0; mt < 2; ++mt) {
                const float x = xs[pass][pt][mt * 32 + l5];
                // (1/2pi) * 10^(-half/8)
                float t0 = x * (half ? 0.11936620731892151f : 0.15915494309189535f);
                #pragma unroll
                for (int ks = 0; ks < 16; ++ks) {
                    const float t1 = t0 * 0.9305720409297085f;   // 10^-1/32
                    const float t2 = t0 * 0.8659643233600653f;   // 10^-2/32
                    const float t3 = t0 * 0.8058421877614819f;   // 10^-3/32
                    uint4v w;
                    w[0] = pack_sc(__builtin_amdgcn_sinf(t0), __builtin_amdgcn_cosf(t0));
                    w[1] = pack_sc(__builtin_amdgcn_sinf(t1), __builtin_amdgcn_cosf(t1));
                    w[2] = pack_sc(__builtin_amdgcn_sinf(t2), __builtin_amdgcn_cosf(t2));
                    w[3] = pack_sc(__builtin_amdgcn_sinf(t3), __builtin_amdgcn_cosf(t3));
                    af[mt][ks] = *(short8*)&w;
                    t0 *= 0.5623413251903491f;                   // 10^-8/32 per ks step
                }
            }

            // ---- GEMM: 8 column tiles of 32; B streamed from LDS, A in regs.
            #pragma unroll
            for (int nt = 0; nt < 8; ++nt) {
                const int o = nt * 32 + l5;
                const int rb = (o << 9) ^ ((o & 7) << 4) ^ (half << 4);
                f32x16 acc0, acc1;
                #pragma unroll
                for (int r = 0; r < 16; ++r) { acc0[r] = 0.f; acc1[r] = 0.f; }
                #pragma unroll
                for (int ks = 0; ks < 16; ++ks) {
                    const short8 bfr = *(const short8*)((const char*)Wlds + (rb ^ (ks << 5)));
                    acc0 = __builtin_amdgcn_mfma_f32_32x32x16_bf16(af[0][ks], bfr, acc0, 0, 0, 0);
                    acc1 = __builtin_amdgcn_mfma_f32_32x32x16_bf16(af[1][ks], bfr, acc1, 0, 0, 0);
                }
                // max over 64 anchor-rows: 32 regs then cross-half shfl.
                float m = fmaxf(acc0[0], acc1[0]);
                #pragma unroll
                for (int r = 1; r < 16; ++r)
                    m = fmaxf(m, fmaxf(acc0[r], acc1[r]));
                m = fmaxf(m, __shfl_down(m, 32));
                if (pass == 0) {
                    dm[p][nt] = m;  // valid on lanes 0..31 (only ones read later)
                } else if (lane < 32) {
                    out[(base + pt) * HH + nt * 32 + l5] = m + dm[p][nt] + bias[nt];
                }
            }
        }
    }
}

extern "C" void kernel_launch(void* const* d_in, const int* in_sizes, int n_in,
                              void* d_out, int out_size, void* d_ws, size_t ws_size,
                              hipStream_t stream) {
    const float* points  = (const float*)d_in[0];
    const float* anchors = (const float*)d_in[1];
    // d_in[2] = cor_score: unused by the reference
    const float* Wa = (const float*)d_in[3];
    const float* ba = (const float*)d_in[4];
    const float* Wd = (const float*)d_in[5];
    const float* bd = (const float*)d_in[6];

    unsigned short* wbf = (unsigned short*)d_ws;  // 256 KB: Wd|Wa bf16

    hipLaunchKernelGGL(prep_w_kernel, dim3(256), dim3(256), 0, stream, Wa, Wd, wbf);
    hipLaunchKernelGGL(cgse_main, dim3(NPTS / BPTS), dim3(512), 0, stream,
                       points, anchors, wbf, ba, bd, (float*)d_out);
}